// Round 18
// baseline (150.751 us; speedup 1.0000x reference)
//
#include <hip/hip_runtime.h>

// Integrator (scaling & squaring) for vel [16,2,512,512] f32, with logdet-Jacobian.
// ROUND-18: THREE dispatches, everything LDS time-tiled, 32x32 core tiles:
//   P1F: init (sobel logdet + K1 from vel in LDS) + K2 + K3   -> records3
//   P2 : K4 + K5                                              -> records5
//   P3F: K6 + K7 + FINAL (ldjac7 + planar f32 output)
// Decoupled schedule: rec_k=(disp_k, ldjac_{k-1}); step: both updates share one
// sample position phi(p, disp_k(p)). Halo reaches: K2..K7 = R17-validated
// (2,2 / 2,2 / 3,4); init vel reach 1; FINAL reach 8 (bound |disp7|<=max|v|~5.7
// -> 7, +1 margin). LDS reuse: dead buffers aliased; cross-phase conflicts
// resolved by register staging (fully unrolled -> static idx, rule #20).
// Buffers: X1 = d_out raw (32MB), X2 = ws. P1F: vel->X1, P2: X1->X2,
// P3F: X2 -> planar f32 d_out (X1 dead by then).

#define NB 16
#define HH 512
#define WW 512
#define HW (HH * WW)
#define TOT (NB * HW)
#define EPS 0.0078125f
#define DISP_ELEMS (NB * 2 * HW)
#define SC (512.0f / 511.0f)

typedef _Float16 f16;
typedef _Float16 f16x4 __attribute__((ext_vector_type(4)));
typedef float f32x2 __attribute__((ext_vector_type(2)));

struct SampC {
    int yc0, xc0, yc1, xc1;   // clamped corner coords (global)
    float w00, w01, w10, w11; // bilinear weights, OOB folded to 0
};

__device__ __forceinline__ SampC make_sampc(float sy, float sx) {
    float fy = floorf(sy), fx = floorf(sx);
    float wy = sy - fy, wx = sx - fx;
    int y0 = (int)fy, x0 = (int)fx;
    int y1 = y0 + 1, x1 = x0 + 1;
    bool xv0 = (unsigned)x0 < (unsigned)WW;
    bool xv1 = (unsigned)x1 < (unsigned)WW;
    bool yv0 = (unsigned)y0 < (unsigned)HH;
    bool yv1 = (unsigned)y1 < (unsigned)HH;
    SampC s;
    s.xc0 = min(max(x0, 0), WW - 1); s.xc1 = min(max(x1, 0), WW - 1);
    s.yc0 = min(max(y0, 0), HH - 1); s.yc1 = min(max(y1, 0), HH - 1);
    float omwx = 1.0f - wx, omwy = 1.0f - wy;
    s.w00 = (xv0 && yv0) ? omwx * omwy : 0.0f;
    s.w01 = (xv1 && yv0) ? wx * omwy   : 0.0f;
    s.w10 = (xv0 && yv1) ? omwx * wy   : 0.0f;
    s.w11 = (xv1 && yv1) ? wx * wy     : 0.0f;
    return s;
}

__device__ __forceinline__ f16x4 step_rec(f16x4 rv, f16x4 g00, f16x4 g01,
                                          f16x4 g10, f16x4 g11, const SampC& s) {
    float d0 = (float)rv.x, d1 = (float)rv.y, l = (float)rv.z;
    float nd0 = d0 + s.w00 * (float)g00.x + s.w01 * (float)g01.x
                   + s.w10 * (float)g10.x + s.w11 * (float)g11.x;
    float nd1 = d1 + s.w00 * (float)g00.y + s.w01 * (float)g01.y
                   + s.w10 * (float)g10.y + s.w11 * (float)g11.y;
    float nl  = l  + s.w00 * (float)g00.z + s.w01 * (float)g01.z
                   + s.w10 * (float)g10.z + s.w11 * (float)g11.z;
    f16x4 w; w.x = (f16)nd0; w.y = (f16)nd1; w.z = (f16)nl; w.w = (f16)0.0f;
    return w;
}

__device__ __forceinline__ float rnd16(float v) { return (float)(f16)v; }

// block -> (img, tile origin); XCD-pinned: XCD c owns images {2c, 2c+1}.
__device__ __forceinline__ void tile_map(int& img, int& ty0, int& tx0) {
    int bidx = blockIdx.x;
    int xcd = bidx & 7, sub = bidx >> 3;       // sub in [0,512)
    img = 2 * xcd + (sub >= 256 ? 1 : 0);
    int tile = sub & 255;
    tx0 = (tile & 15) << 5;
    ty0 = (tile >> 4) << 5;
}

// ---------------- P1F: init + K2 + K3 ----------------
// VEL f32x2[42][43] (14448B) ; REC f16x4[40][41] (13120B) ; MID aliases VEL.
__global__ void __launch_bounds__(256, 4) p1_fused(const float* __restrict__ vel,
                                                   f16x4* __restrict__ rdst) {
    __shared__ __align__(16) char smemV[42 * 43 * 8];
    __shared__ __align__(16) f16x4 REC[40][41];
    f32x2 (*VEL)[43] = (f32x2 (*)[43])smemV;
    f16x4 (*MID)[37] = (f16x4 (*)[37])smemV;

    int img, ty0, tx0;
    tile_map(img, ty0, tx0);
    int t = threadIdx.x;

    const float* v0 = vel + (size_t)img * 2 * HW;
    const float* v1 = v0 + HW;

    // phase 0: load vel ext tile (core+5), replicate-clamped
    for (int i = t; i < 42 * 42; i += 256) {
        int ey = i / 42, ex = i - ey * 42;
        int gy = min(max(ty0 - 5 + ey, 0), HH - 1);
        int gx = min(max(tx0 - 5 + ex, 0), WW - 1);
        f32x2 v; v.x = v0[gy * WW + gx]; v.y = v1[gy * WW + gx];
        VEL[ey][ex] = v;
    }
    __syncthreads();

    // phase 1: records1 = (disp1, ldjac0) on core+4 (40x40)
    {
        const int oy = ty0 - 5, ox = tx0 - 5;
        for (int i = t; i < 1600; i += 256) {
            int ry = i / 40, rx = i - ry * 40;
            int qy = ty0 - 4 + ry, qx = tx0 - 4 + rx;
            // 3x3 window (VEL idx = global - origin; window = [ry..ry+2])
            f32x2 w00 = VEL[ry][rx],     w01 = VEL[ry][rx + 1],     w02 = VEL[ry][rx + 2];
            f32x2 w10 = VEL[ry + 1][rx], w11 = VEL[ry + 1][rx + 1], w12 = VEL[ry + 1][rx + 2];
            f32x2 w20 = VEL[ry + 2][rx], w21 = VEL[ry + 2][rx + 1], w22 = VEL[ry + 2][rx + 2];

            float a = 0.125f * ((w20.x + 2.0f * w21.x + w22.x) - (w00.x + 2.0f * w01.x + w02.x));
            float b = 0.125f * ((w02.x + 2.0f * w12.x + w22.x) - (w00.x + 2.0f * w10.x + w20.x));
            float c = 0.125f * ((w20.y + 2.0f * w21.y + w22.y) - (w00.y + 2.0f * w01.y + w02.y));
            float d = 0.125f * ((w02.y + 2.0f * w12.y + w22.y) - (w00.y + 2.0f * w10.y + w20.y));

            float xa = a, xb = b, xc = c, xd = d;
            float ld = EPS * (xa + xd);
            float na = xa * a + xb * c, nb = xa * b + xb * d;
            float nc = xc * a + xd * c, nd = xc * b + xd * d;
            xa = na; xb = nb; xc = nc; xd = nd;
            ld -= (EPS * EPS) * (xa + xd) * 0.5f;
            na = xa * a + xb * c; nb = xa * b + xb * d;
            nc = xc * a + xd * c; nd = xc * b + xd * d;
            xa = na; xb = nb; xc = nc; xd = nd;
            ld += (EPS * EPS * EPS) * (xa + xd) * (1.0f / 3.0f);
            na = xa * a + xb * c;
            nd = xc * b + xd * d;
            ld -= (EPS * EPS * EPS * EPS) * (na + nd) * 0.25f;

            float d0 = rnd16(EPS * w11.x);
            float d1 = rnd16(EPS * w11.y);

            float sy = fmaf((float)qy + d0, SC, -0.5f);
            float sx = fmaf((float)qx + d1, SC, -0.5f);
            SampC s = make_sampc(sy, sx);

            f32x2 c00 = VEL[s.yc0 - oy][s.xc0 - ox];
            f32x2 c01 = VEL[s.yc0 - oy][s.xc1 - ox];
            f32x2 c10 = VEL[s.yc1 - oy][s.xc0 - ox];
            f32x2 c11 = VEL[s.yc1 - oy][s.xc1 - ox];

            float nd0 = d0 + s.w00 * rnd16(EPS * c00.x) + s.w01 * rnd16(EPS * c01.x)
                           + s.w10 * rnd16(EPS * c10.x) + s.w11 * rnd16(EPS * c11.x);
            float nd1 = d1 + s.w00 * rnd16(EPS * c00.y) + s.w01 * rnd16(EPS * c01.y)
                           + s.w10 * rnd16(EPS * c10.y) + s.w11 * rnd16(EPS * c11.y);

            f16x4 rec; rec.x = (f16)nd0; rec.y = (f16)nd1; rec.z = (f16)ld; rec.w = (f16)0.0f;
            REC[ry][rx] = rec;
        }
    }
    __syncthreads();   // VEL dead from here; MID may overwrite it

    // phase 2: K2 on core+2 (36x36), read REC, write MID (aliases VEL — safe)
    {
        const int oy = ty0 - 4, ox = tx0 - 4;
        for (int i = t; i < 1296; i += 256) {
            int my = i / 36, mx = i - my * 36;
            int qy = ty0 - 2 + my, qx = tx0 - 2 + mx;
            f16x4 rv = REC[my + 2][mx + 2];
            float sy = fmaf((float)qy + (float)rv.x, SC, -0.5f);
            float sx = fmaf((float)qx + (float)rv.y, SC, -0.5f);
            SampC s = make_sampc(sy, sx);
            f16x4 g00 = REC[s.yc0 - oy][s.xc0 - ox];
            f16x4 g01 = REC[s.yc0 - oy][s.xc1 - ox];
            f16x4 g10 = REC[s.yc1 - oy][s.xc0 - ox];
            f16x4 g11 = REC[s.yc1 - oy][s.xc1 - ox];
            MID[my][mx] = step_rec(rv, g00, g01, g10, g11, s);
        }
    }
    __syncthreads();

    // phase 3: K3 on core, read MID, write records3 to global
    {
        const int oy = ty0 - 2, ox = tx0 - 2;
        f16x4* wp = rdst + (size_t)img * HW;
        for (int i = t; i < 1024; i += 256) {
            int cy = i >> 5, cx = i & 31;
            int qy = ty0 + cy, qx = tx0 + cx;
            f16x4 rv = MID[cy + 2][cx + 2];
            float sy = fmaf((float)qy + (float)rv.x, SC, -0.5f);
            float sx = fmaf((float)qx + (float)rv.y, SC, -0.5f);
            SampC s = make_sampc(sy, sx);
            f16x4 g00 = MID[s.yc0 - oy][s.xc0 - ox];
            f16x4 g01 = MID[s.yc0 - oy][s.xc1 - ox];
            f16x4 g10 = MID[s.yc1 - oy][s.xc0 - ox];
            f16x4 g11 = MID[s.yc1 - oy][s.xc1 - ox];
            wp[qy * WW + qx] = step_rec(rv, g00, g01, g10, g11, s);
        }
    }
}

// ---------------- P2: K4 + K5 (single 13.1KB buffer, staged K4) ----------------
__global__ void __launch_bounds__(256, 6) p2_pair(const f16x4* __restrict__ rsrc,
                                                  f16x4* __restrict__ rdst) {
    __shared__ __align__(16) char smem[40 * 41 * 8];
    f16x4 (*IN)[41]  = (f16x4 (*)[41])smem;
    f16x4 (*MID)[37] = (f16x4 (*)[37])smem;   // overwrites IN after staging

    int img, ty0, tx0;
    tile_map(img, ty0, tx0);
    int t = threadIdx.x;
    const f16x4* rp = rsrc + (size_t)img * HW;

    // load records3 ext (core+4)
    for (int i = t; i < 1600; i += 256) {
        int ey = i / 40, ex = i - ey * 40;
        int gy = min(max(ty0 - 4 + ey, 0), HH - 1);
        int gx = min(max(tx0 - 4 + ex, 0), WW - 1);
        IN[ey][ex] = rp[gy * WW + gx];
    }
    __syncthreads();

    // K4 on core+2 (36x36) -> registers (fully unrolled, static idx)
    f16x4 st[6];
    {
        const int oy = ty0 - 4, ox = tx0 - 4;
#pragma unroll
        for (int k = 0; k < 6; ++k) {
            int i = t + (k << 8);
            if (i < 1296) {
                int my = i / 36, mx = i - my * 36;
                int qy = ty0 - 2 + my, qx = tx0 - 2 + mx;
                f16x4 rv = IN[my + 2][mx + 2];
                float sy = fmaf((float)qy + (float)rv.x, SC, -0.5f);
                float sx = fmaf((float)qx + (float)rv.y, SC, -0.5f);
                SampC s = make_sampc(sy, sx);
                f16x4 g00 = IN[s.yc0 - oy][s.xc0 - ox];
                f16x4 g01 = IN[s.yc0 - oy][s.xc1 - ox];
                f16x4 g10 = IN[s.yc1 - oy][s.xc0 - ox];
                f16x4 g11 = IN[s.yc1 - oy][s.xc1 - ox];
                st[k] = step_rec(rv, g00, g01, g10, g11, s);
            }
        }
    }
    __syncthreads();
#pragma unroll
    for (int k = 0; k < 6; ++k) {
        int i = t + (k << 8);
        if (i < 1296) MID[i / 36][i - (i / 36) * 36] = st[k];
    }
    __syncthreads();

    // K5 on core -> global records5
    {
        const int oy = ty0 - 2, ox = tx0 - 2;
        f16x4* wp = rdst + (size_t)img * HW;
        for (int i = t; i < 1024; i += 256) {
            int cy = i >> 5, cx = i & 31;
            int qy = ty0 + cy, qx = tx0 + cx;
            f16x4 rv = MID[cy + 2][cx + 2];
            float sy = fmaf((float)qy + (float)rv.x, SC, -0.5f);
            float sx = fmaf((float)qx + (float)rv.y, SC, -0.5f);
            SampC s = make_sampc(sy, sx);
            f16x4 g00 = MID[s.yc0 - oy][s.xc0 - ox];
            f16x4 g01 = MID[s.yc0 - oy][s.xc1 - ox];
            f16x4 g10 = MID[s.yc1 - oy][s.xc0 - ox];
            f16x4 g11 = MID[s.yc1 - oy][s.xc1 - ox];
            wp[qy * WW + qx] = step_rec(rv, g00, g01, g10, g11, s);
        }
    }
}

// ---------------- P3F: K6 + K7 + FINAL (31.2KB buffer, staged K6/K7) ----------------
// reaches: K6=3 (|disp5|<=1.4), K7=4 (|disp6|<=2.8), FINAL=8 (|disp7|<=max|v|+margin)
__global__ void __launch_bounds__(256, 4) p3_fused(const f16x4* __restrict__ rsrc,
                                                   float* __restrict__ doutp,
                                                   float* __restrict__ loutp) {
    __shared__ __align__(16) char smem[62 * 63 * 8];
    f16x4 (*IN)[63] = (f16x4 (*)[63])smem;
    f16x4 (*M1)[57] = (f16x4 (*)[57])smem;
    f16x4 (*M2)[49] = (f16x4 (*)[49])smem;

    int img, ty0, tx0;
    tile_map(img, ty0, tx0);
    int t = threadIdx.x;
    const f16x4* rp = rsrc + (size_t)img * HW;

    // load records5 ext (core+15 = 62x62)
    for (int i = t; i < 62 * 62; i += 256) {
        int ey = i / 62, ex = i - ey * 62;
        int gy = min(max(ty0 - 15 + ey, 0), HH - 1);
        int gx = min(max(tx0 - 15 + ex, 0), WW - 1);
        IN[ey][ex] = rp[gy * WW + gx];
    }
    __syncthreads();

    // K6 on core+12 (56x56) -> registers
    f16x4 st1[13];
    {
        const int oy = ty0 - 15, ox = tx0 - 15;
#pragma unroll
        for (int k = 0; k < 13; ++k) {
            int i = t + (k << 8);
            if (i < 3136) {
                int my = i / 56, mx = i - my * 56;
                int qy = ty0 - 12 + my, qx = tx0 - 12 + mx;
                f16x4 rv = IN[my + 3][mx + 3];
                float sy = fmaf((float)qy + (float)rv.x, SC, -0.5f);
                float sx = fmaf((float)qx + (float)rv.y, SC, -0.5f);
                SampC s = make_sampc(sy, sx);
                f16x4 g00 = IN[s.yc0 - oy][s.xc0 - ox];
                f16x4 g01 = IN[s.yc0 - oy][s.xc1 - ox];
                f16x4 g10 = IN[s.yc1 - oy][s.xc0 - ox];
                f16x4 g11 = IN[s.yc1 - oy][s.xc1 - ox];
                st1[k] = step_rec(rv, g00, g01, g10, g11, s);
            }
        }
    }
    __syncthreads();
#pragma unroll
    for (int k = 0; k < 13; ++k) {
        int i = t + (k << 8);
        if (i < 3136) M1[i / 56][i - (i / 56) * 56] = st1[k];
    }
    __syncthreads();

    // K7 on core+8 (48x48) -> registers
    f16x4 st2[9];
    {
        const int oy = ty0 - 12, ox = tx0 - 12;
#pragma unroll
        for (int k = 0; k < 9; ++k) {
            int i = t + (k << 8);
            if (i < 2304) {
                int my = i / 48, mx = i - my * 48;
                int qy = ty0 - 8 + my, qx = tx0 - 8 + mx;
                f16x4 rv = M1[my + 4][mx + 4];
                float sy = fmaf((float)qy + (float)rv.x, SC, -0.5f);
                float sx = fmaf((float)qx + (float)rv.y, SC, -0.5f);
                SampC s = make_sampc(sy, sx);
                f16x4 g00 = M1[s.yc0 - oy][s.xc0 - ox];
                f16x4 g01 = M1[s.yc0 - oy][s.xc1 - ox];
                f16x4 g10 = M1[s.yc1 - oy][s.xc0 - ox];
                f16x4 g11 = M1[s.yc1 - oy][s.xc1 - ox];
                st2[k] = step_rec(rv, g00, g01, g10, g11, s);
            }
        }
    }
    __syncthreads();
#pragma unroll
    for (int k = 0; k < 9; ++k) {
        int i = t + (k << 8);
        if (i < 2304) M2[i / 48][i - (i / 48) * 48] = st2[k];
    }
    __syncthreads();

    // FINAL on core: ldjac7 = ldjac6 + bilerp(ldjac6, phi(p, disp7)); planar f32 out
    {
        const int oy = ty0 - 8, ox = tx0 - 8;
        float* pd = doutp + (size_t)img * 2 * HW;
        float* pl = loutp + (size_t)img * HW;
        for (int i = t; i < 1024; i += 256) {
            int cy = i >> 5, cx = i & 31;
            int qy = ty0 + cy, qx = tx0 + cx;
            f16x4 rv = M2[cy + 8][cx + 8];
            float d0 = (float)rv.x, d1 = (float)rv.y, l = (float)rv.z;
            float sy = fmaf((float)qy + d0, SC, -0.5f);
            float sx = fmaf((float)qx + d1, SC, -0.5f);
            SampC s = make_sampc(sy, sx);
            f16x4 g00 = M2[s.yc0 - oy][s.xc0 - ox];
            f16x4 g01 = M2[s.yc0 - oy][s.xc1 - ox];
            f16x4 g10 = M2[s.yc1 - oy][s.xc0 - ox];
            f16x4 g11 = M2[s.yc1 - oy][s.xc1 - ox];
            float nl = l + s.w00 * (float)g00.z + s.w01 * (float)g01.z
                         + s.w10 * (float)g10.z + s.w11 * (float)g11.z;
            pd[qy * WW + qx]      = d0;
            pd[HW + qy * WW + qx] = d1;
            pl[qy * WW + qx]      = nl;
        }
    }
}

extern "C" void kernel_launch(void* const* d_in, const int* in_sizes, int n_in,
                              void* d_out, int out_size, void* d_ws, size_t ws_size,
                              hipStream_t stream) {
    const float* vel = (const float*)d_in[0];
    float* out = (float*)d_out;

    f16x4* rX1 = (f16x4*)d_out;   // records3 scratch (32MB raw in d_out)
    f16x4* rX2 = (f16x4*)d_ws;    // records5 scratch (32MB in ws)

    dim3 block(256), grid(4096);  // 16 img x 256 tiles

    // P1F: vel -> records3 (X1)
    p1_fused<<<grid, block, 0, stream>>>(vel, rX1);
    // P2: records3 (X1) -> records5 (X2)
    p2_pair<<<grid, block, 0, stream>>>(rX1, rX2);
    // P3F: records5 (X2) -> planar f32 d_out (X1 dead; overwrite is safe)
    p3_fused<<<grid, block, 0, stream>>>(rX2, out, out + DISP_ELEMS);
}

// Round 19
// 124.705 us; speedup vs baseline: 1.2089x; 1.2089x over previous
//
#include <hip/hip_runtime.h>

// Integrator (scaling & squaring) for vel [16,2,512,512] f32, with logdet-Jacobian.
// ROUND-19: keep R18's winning FRONT fusion, revert the back to R17's validated
// pieces. 4 dispatches, 32x32 core LDS time-tiles:
//   P1F: init (sobel logdet + K1 from vel in LDS) + K2 + K3   vel    -> R3 (ws)
//   P2 : K4 + K5 (single-buffer, register-staged)             R3     -> R5 (d_out raw)
//   P3 : K6 + K7 pair (reaches 3/4, separate IN/MID)          R5     -> R7 (ws)
//   FINAL: streaming ldjac7 + planar f32 output               R7     -> d_out
// (R18's p3_fused regressed: FINAL reach-8 halo => 6.3x compute amplification,
//  VALUBusy 67%. R17's P3-pair + streaming FINAL are both near their floors.)
// Records rec_k=(disp_k.y, disp_k.x, ldjac_{k-1}, 0) f16x4; decoupled schedule:
// disp_{k+1} and ldjac_k share one sample position phi(p, disp_k(p)).

#define NB 16
#define HH 512
#define WW 512
#define HW (HH * WW)
#define TOT (NB * HW)
#define EPS 0.0078125f
#define DISP_ELEMS (NB * 2 * HW)
#define SC (512.0f / 511.0f)

typedef _Float16 f16;
typedef _Float16 f16x4 __attribute__((ext_vector_type(4)));
typedef float f32x2 __attribute__((ext_vector_type(2)));

struct SampC {
    int yc0, xc0, yc1, xc1;   // clamped corner coords (global)
    float w00, w01, w10, w11; // bilinear weights, OOB folded to 0
};

__device__ __forceinline__ SampC make_sampc(float sy, float sx) {
    float fy = floorf(sy), fx = floorf(sx);
    float wy = sy - fy, wx = sx - fx;
    int y0 = (int)fy, x0 = (int)fx;
    int y1 = y0 + 1, x1 = x0 + 1;
    bool xv0 = (unsigned)x0 < (unsigned)WW;
    bool xv1 = (unsigned)x1 < (unsigned)WW;
    bool yv0 = (unsigned)y0 < (unsigned)HH;
    bool yv1 = (unsigned)y1 < (unsigned)HH;
    SampC s;
    s.xc0 = min(max(x0, 0), WW - 1); s.xc1 = min(max(x1, 0), WW - 1);
    s.yc0 = min(max(y0, 0), HH - 1); s.yc1 = min(max(y1, 0), HH - 1);
    float omwx = 1.0f - wx, omwy = 1.0f - wy;
    s.w00 = (xv0 && yv0) ? omwx * omwy : 0.0f;
    s.w01 = (xv1 && yv0) ? wx * omwy   : 0.0f;
    s.w10 = (xv0 && yv1) ? omwx * wy   : 0.0f;
    s.w11 = (xv1 && yv1) ? wx * wy     : 0.0f;
    return s;
}

__device__ __forceinline__ f16x4 step_rec(f16x4 rv, f16x4 g00, f16x4 g01,
                                          f16x4 g10, f16x4 g11, const SampC& s) {
    float d0 = (float)rv.x, d1 = (float)rv.y, l = (float)rv.z;
    float nd0 = d0 + s.w00 * (float)g00.x + s.w01 * (float)g01.x
                   + s.w10 * (float)g10.x + s.w11 * (float)g11.x;
    float nd1 = d1 + s.w00 * (float)g00.y + s.w01 * (float)g01.y
                   + s.w10 * (float)g10.y + s.w11 * (float)g11.y;
    float nl  = l  + s.w00 * (float)g00.z + s.w01 * (float)g01.z
                   + s.w10 * (float)g10.z + s.w11 * (float)g11.z;
    f16x4 w; w.x = (f16)nd0; w.y = (f16)nd1; w.z = (f16)nl; w.w = (f16)0.0f;
    return w;
}

__device__ __forceinline__ float rnd16(float v) { return (float)(f16)v; }

// block -> (img, tile origin); XCD-pinned: XCD c owns images {2c, 2c+1}.
__device__ __forceinline__ void tile_map(int& img, int& ty0, int& tx0) {
    int bidx = blockIdx.x;
    int xcd = bidx & 7, sub = bidx >> 3;       // sub in [0,512)
    img = 2 * xcd + (sub >= 256 ? 1 : 0);
    int tile = sub & 255;
    tx0 = (tile & 15) << 5;
    ty0 = (tile >> 4) << 5;
}

// XCD-remapped flat index for the streaming FINAL (16384 blocks).
__device__ __forceinline__ int remap_idx() {
    int bid = blockIdx.x;
    int task = ((bid & 7) << 11) | (bid >> 3);
    return task * 256 + threadIdx.x;
}

// ---------------- P1F: init + K2 + K3 ----------------
// VEL f32x2[42][43] (14448B) ; REC f16x4[40][41] (13120B) ; MID aliases VEL.
__global__ void __launch_bounds__(256, 4) p1_fused(const float* __restrict__ vel,
                                                   f16x4* __restrict__ rdst) {
    __shared__ __align__(16) char smemV[42 * 43 * 8];
    __shared__ __align__(16) f16x4 REC[40][41];
    f32x2 (*VEL)[43] = (f32x2 (*)[43])smemV;
    f16x4 (*MID)[37] = (f16x4 (*)[37])smemV;

    int img, ty0, tx0;
    tile_map(img, ty0, tx0);
    int t = threadIdx.x;

    const float* v0 = vel + (size_t)img * 2 * HW;
    const float* v1 = v0 + HW;

    // phase 0: load vel ext tile (core+5), replicate-clamped
    for (int i = t; i < 42 * 42; i += 256) {
        int ey = i / 42, ex = i - ey * 42;
        int gy = min(max(ty0 - 5 + ey, 0), HH - 1);
        int gx = min(max(tx0 - 5 + ex, 0), WW - 1);
        f32x2 v; v.x = v0[gy * WW + gx]; v.y = v1[gy * WW + gx];
        VEL[ey][ex] = v;
    }
    __syncthreads();

    // phase 1: records1 = (disp1, ldjac0) on core+4 (40x40)
    {
        const int oy = ty0 - 5, ox = tx0 - 5;
        for (int i = t; i < 1600; i += 256) {
            int ry = i / 40, rx = i - ry * 40;
            int qy = ty0 - 4 + ry, qx = tx0 - 4 + rx;
            f32x2 w00 = VEL[ry][rx],     w01 = VEL[ry][rx + 1],     w02 = VEL[ry][rx + 2];
            f32x2 w10 = VEL[ry + 1][rx], w11 = VEL[ry + 1][rx + 1], w12 = VEL[ry + 1][rx + 2];
            f32x2 w20 = VEL[ry + 2][rx], w21 = VEL[ry + 2][rx + 1], w22 = VEL[ry + 2][rx + 2];

            float a = 0.125f * ((w20.x + 2.0f * w21.x + w22.x) - (w00.x + 2.0f * w01.x + w02.x));
            float b = 0.125f * ((w02.x + 2.0f * w12.x + w22.x) - (w00.x + 2.0f * w10.x + w20.x));
            float c = 0.125f * ((w20.y + 2.0f * w21.y + w22.y) - (w00.y + 2.0f * w01.y + w02.y));
            float d = 0.125f * ((w02.y + 2.0f * w12.y + w22.y) - (w00.y + 2.0f * w10.y + w20.y));

            float xa = a, xb = b, xc = c, xd = d;
            float ld = EPS * (xa + xd);
            float na = xa * a + xb * c, nb = xa * b + xb * d;
            float nc = xc * a + xd * c, nd = xc * b + xd * d;
            xa = na; xb = nb; xc = nc; xd = nd;
            ld -= (EPS * EPS) * (xa + xd) * 0.5f;
            na = xa * a + xb * c; nb = xa * b + xb * d;
            nc = xc * a + xd * c; nd = xc * b + xd * d;
            xa = na; xb = nb; xc = nc; xd = nd;
            ld += (EPS * EPS * EPS) * (xa + xd) * (1.0f / 3.0f);
            na = xa * a + xb * c;
            nd = xc * b + xd * d;
            ld -= (EPS * EPS * EPS * EPS) * (na + nd) * 0.25f;

            float d0 = rnd16(EPS * w11.x);
            float d1 = rnd16(EPS * w11.y);

            float sy = fmaf((float)qy + d0, SC, -0.5f);
            float sx = fmaf((float)qx + d1, SC, -0.5f);
            SampC s = make_sampc(sy, sx);

            f32x2 c00 = VEL[s.yc0 - oy][s.xc0 - ox];
            f32x2 c01 = VEL[s.yc0 - oy][s.xc1 - ox];
            f32x2 c10 = VEL[s.yc1 - oy][s.xc0 - ox];
            f32x2 c11 = VEL[s.yc1 - oy][s.xc1 - ox];

            float nd0 = d0 + s.w00 * rnd16(EPS * c00.x) + s.w01 * rnd16(EPS * c01.x)
                           + s.w10 * rnd16(EPS * c10.x) + s.w11 * rnd16(EPS * c11.x);
            float nd1 = d1 + s.w00 * rnd16(EPS * c00.y) + s.w01 * rnd16(EPS * c01.y)
                           + s.w10 * rnd16(EPS * c10.y) + s.w11 * rnd16(EPS * c11.y);

            f16x4 rec; rec.x = (f16)nd0; rec.y = (f16)nd1; rec.z = (f16)ld; rec.w = (f16)0.0f;
            REC[ry][rx] = rec;
        }
    }
    __syncthreads();   // VEL dead from here; MID may overwrite it

    // phase 2: K2 on core+2 (36x36), read REC, write MID (aliases VEL — safe)
    {
        const int oy = ty0 - 4, ox = tx0 - 4;
        for (int i = t; i < 1296; i += 256) {
            int my = i / 36, mx = i - my * 36;
            int qy = ty0 - 2 + my, qx = tx0 - 2 + mx;
            f16x4 rv = REC[my + 2][mx + 2];
            float sy = fmaf((float)qy + (float)rv.x, SC, -0.5f);
            float sx = fmaf((float)qx + (float)rv.y, SC, -0.5f);
            SampC s = make_sampc(sy, sx);
            f16x4 g00 = REC[s.yc0 - oy][s.xc0 - ox];
            f16x4 g01 = REC[s.yc0 - oy][s.xc1 - ox];
            f16x4 g10 = REC[s.yc1 - oy][s.xc0 - ox];
            f16x4 g11 = REC[s.yc1 - oy][s.xc1 - ox];
            MID[my][mx] = step_rec(rv, g00, g01, g10, g11, s);
        }
    }
    __syncthreads();

    // phase 3: K3 on core, read MID, write records3 to global
    {
        const int oy = ty0 - 2, ox = tx0 - 2;
        f16x4* wp = rdst + (size_t)img * HW;
        for (int i = t; i < 1024; i += 256) {
            int cy = i >> 5, cx = i & 31;
            int qy = ty0 + cy, qx = tx0 + cx;
            f16x4 rv = MID[cy + 2][cx + 2];
            float sy = fmaf((float)qy + (float)rv.x, SC, -0.5f);
            float sx = fmaf((float)qx + (float)rv.y, SC, -0.5f);
            SampC s = make_sampc(sy, sx);
            f16x4 g00 = MID[s.yc0 - oy][s.xc0 - ox];
            f16x4 g01 = MID[s.yc0 - oy][s.xc1 - ox];
            f16x4 g10 = MID[s.yc1 - oy][s.xc0 - ox];
            f16x4 g11 = MID[s.yc1 - oy][s.xc1 - ox];
            wp[qy * WW + qx] = step_rec(rv, g00, g01, g10, g11, s);
        }
    }
}

// ---------------- P2: K4 + K5 (single 13.1KB buffer, staged K4) ----------------
__global__ void __launch_bounds__(256, 6) p2_pair(const f16x4* __restrict__ rsrc,
                                                  f16x4* __restrict__ rdst) {
    __shared__ __align__(16) char smem[40 * 41 * 8];
    f16x4 (*IN)[41]  = (f16x4 (*)[41])smem;
    f16x4 (*MID)[37] = (f16x4 (*)[37])smem;   // overwrites IN after staging

    int img, ty0, tx0;
    tile_map(img, ty0, tx0);
    int t = threadIdx.x;
    const f16x4* rp = rsrc + (size_t)img * HW;

    // load records3 ext (core+4)
    for (int i = t; i < 1600; i += 256) {
        int ey = i / 40, ex = i - ey * 40;
        int gy = min(max(ty0 - 4 + ey, 0), HH - 1);
        int gx = min(max(tx0 - 4 + ex, 0), WW - 1);
        IN[ey][ex] = rp[gy * WW + gx];
    }
    __syncthreads();

    // K4 on core+2 (36x36) -> registers (fully unrolled, static idx)
    f16x4 st[6];
    {
        const int oy = ty0 - 4, ox = tx0 - 4;
#pragma unroll
        for (int k = 0; k < 6; ++k) {
            int i = t + (k << 8);
            if (i < 1296) {
                int my = i / 36, mx = i - my * 36;
                int qy = ty0 - 2 + my, qx = tx0 - 2 + mx;
                f16x4 rv = IN[my + 2][mx + 2];
                float sy = fmaf((float)qy + (float)rv.x, SC, -0.5f);
                float sx = fmaf((float)qx + (float)rv.y, SC, -0.5f);
                SampC s = make_sampc(sy, sx);
                f16x4 g00 = IN[s.yc0 - oy][s.xc0 - ox];
                f16x4 g01 = IN[s.yc0 - oy][s.xc1 - ox];
                f16x4 g10 = IN[s.yc1 - oy][s.xc0 - ox];
                f16x4 g11 = IN[s.yc1 - oy][s.xc1 - ox];
                st[k] = step_rec(rv, g00, g01, g10, g11, s);
            }
        }
    }
    __syncthreads();
#pragma unroll
    for (int k = 0; k < 6; ++k) {
        int i = t + (k << 8);
        if (i < 1296) MID[i / 36][i - (i / 36) * 36] = st[k];
    }
    __syncthreads();

    // K5 on core -> global records5
    {
        const int oy = ty0 - 2, ox = tx0 - 2;
        f16x4* wp = rdst + (size_t)img * HW;
        for (int i = t; i < 1024; i += 256) {
            int cy = i >> 5, cx = i & 31;
            int qy = ty0 + cy, qx = tx0 + cx;
            f16x4 rv = MID[cy + 2][cx + 2];
            float sy = fmaf((float)qy + (float)rv.x, SC, -0.5f);
            float sx = fmaf((float)qx + (float)rv.y, SC, -0.5f);
            SampC s = make_sampc(sy, sx);
            f16x4 g00 = MID[s.yc0 - oy][s.xc0 - ox];
            f16x4 g01 = MID[s.yc0 - oy][s.xc1 - ox];
            f16x4 g10 = MID[s.yc1 - oy][s.xc0 - ox];
            f16x4 g11 = MID[s.yc1 - oy][s.xc1 - ox];
            wp[qy * WW + qx] = step_rec(rv, g00, g01, g10, g11, s);
        }
    }
}

// ---------------- P3: K6 + K7 pair (R17-validated, reaches 3/4) ----------------
// IN f16x4[46][47] (17.3KB) ; MID f16x4[40][41] (13.1KB) ; 30.4KB -> 5 blk/CU
__global__ void __launch_bounds__(256, 4) p3_pair(const f16x4* __restrict__ rsrc,
                                                  f16x4* __restrict__ rdst) {
    constexpr int R1 = 3, R2 = 4;
    constexpr int MW = 32 + 2 * R2, MH = MW;            // 40
    constexpr int EW = 32 + 2 * (R1 + R2), EH = EW;     // 46
    __shared__ f16x4 IN[EH][EW + 1];
    __shared__ f16x4 MID[MH][MW + 1];

    int img, ty0, tx0;
    tile_map(img, ty0, tx0);
    int t = threadIdx.x;
    const f16x4* rp = rsrc + (size_t)img * HW;

    // load records5 ext (core+7)
    for (int i = t; i < EH * EW; i += 256) {
        int ey = i / EW, ex = i - ey * EW;
        int iy = min(max(ty0 - (R1 + R2) + ey, 0), HH - 1);
        int ix = min(max(tx0 - (R1 + R2) + ex, 0), WW - 1);
        IN[ey][ex] = rp[iy * WW + ix];
    }
    __syncthreads();

    // K6 on core+4 (40x40), gathers from IN (reach 3)
    {
        const int oy = ty0 - (R1 + R2), ox = tx0 - (R1 + R2);
        for (int i = t; i < MH * MW; i += 256) {
            int my = i / MW, mx = i - my * MW;
            int qy = ty0 - R2 + my, qx = tx0 - R2 + mx;
            f16x4 rv = IN[my + R1][mx + R1];
            float sy = fmaf((float)qy + (float)rv.x, SC, -0.5f);
            float sx = fmaf((float)qx + (float)rv.y, SC, -0.5f);
            SampC s = make_sampc(sy, sx);
            f16x4 g00 = IN[s.yc0 - oy][s.xc0 - ox];
            f16x4 g01 = IN[s.yc0 - oy][s.xc1 - ox];
            f16x4 g10 = IN[s.yc1 - oy][s.xc0 - ox];
            f16x4 g11 = IN[s.yc1 - oy][s.xc1 - ox];
            MID[my][mx] = step_rec(rv, g00, g01, g10, g11, s);
        }
    }
    __syncthreads();

    // K7 on core, gathers from MID (reach 4), write records7 to global
    {
        const int oy = ty0 - R2, ox = tx0 - R2;
        f16x4* wp = rdst + (size_t)img * HW;
        for (int i = t; i < 1024; i += 256) {
            int cy = i >> 5, cx = i & 31;
            int qy = ty0 + cy, qx = tx0 + cx;
            f16x4 rv = MID[cy + R2][cx + R2];
            float sy = fmaf((float)qy + (float)rv.x, SC, -0.5f);
            float sx = fmaf((float)qx + (float)rv.y, SC, -0.5f);
            SampC s = make_sampc(sy, sx);
            f16x4 g00 = MID[s.yc0 - oy][s.xc0 - ox];
            f16x4 g01 = MID[s.yc0 - oy][s.xc1 - ox];
            f16x4 g10 = MID[s.yc1 - oy][s.xc0 - ox];
            f16x4 g11 = MID[s.yc1 - oy][s.xc1 - ox];
            wp[qy * WW + qx] = step_rec(rv, g00, g01, g10, g11, s);
        }
    }
}

// ---------------- FINAL: streaming ldjac7 + planar f32 output ----------------
__global__ void __launch_bounds__(256) step_final(const f16x4* __restrict__ rsrc,
                                                  float* __restrict__ doutp,
                                                  float* __restrict__ loutp) {
    int idx = remap_idx();
    int n = idx >> 18;
    int rem = idx & (HW - 1);
    int y = rem >> 9, x = rem & (WW - 1);

    const f16x4* rp = rsrc + (size_t)n * HW;

    f16x4 rv = rp[rem];
    float d0 = (float)rv.x, d1 = (float)rv.y, l = (float)rv.z;

    float sy = fmaf((float)y + d0, SC, -0.5f);
    float sx = fmaf((float)x + d1, SC, -0.5f);
    SampC s = make_sampc(sy, sx);

    f16x4 g00 = rp[s.yc0 * WW + s.xc0], g01 = rp[s.yc0 * WW + s.xc1];
    f16x4 g10 = rp[s.yc1 * WW + s.xc0], g11 = rp[s.yc1 * WW + s.xc1];

    float nl = l + s.w00 * (float)g00.z + s.w01 * (float)g01.z
                 + s.w10 * (float)g10.z + s.w11 * (float)g11.z;

    float* pd = doutp + (size_t)n * 2 * HW;
    pd[rem]      = d0;
    pd[HW + rem] = d1;
    loutp[(size_t)n * HW + rem] = nl;
}

extern "C" void kernel_launch(void* const* d_in, const int* in_sizes, int n_in,
                              void* d_out, int out_size, void* d_ws, size_t ws_size,
                              hipStream_t stream) {
    const float* vel = (const float*)d_in[0];
    float* out = (float*)d_out;

    // Buffer rotation (each record set = 32MB):
    //   R3 = ws, R5 = d_out raw, R7 = ws (records3 dead), FINAL -> d_out planar.
    f16x4* rWS  = (f16x4*)d_ws;
    f16x4* rOUT = (f16x4*)d_out;

    dim3 block(256), gridT(4096);   // 16 img x 256 tiles

    p1_fused<<<gridT, block, 0, stream>>>(vel, rWS);             // vel -> R3 (ws)
    p2_pair<<<gridT, block, 0, stream>>>(rWS, rOUT);             // R3 -> R5 (d_out raw)
    p3_pair<<<gridT, block, 0, stream>>>(rOUT, rWS);             // R5 -> R7 (ws)
    step_final<<<dim3(TOT / 256), block, 0, stream>>>(rWS, out, out + DISP_ELEMS);
}